// Round 9
// baseline (518.974 us; speedup 1.0000x reference)
//
#include <hip/hip_runtime.h>

// GATv2 3-layer + mean-pool + linear head, MI355X.
// R8: gemm LDS fixed — weights pre-transposed once into ws (k-major), both
// tiles +1-padded (stride 65). Kills the 4.2M/dispatch bank conflicts from
// R3's broken XOR swizzle and the 48 scalar ds_writes/thread transpose.

#define NN 50000
#define NE 1000000
#define HID 64
#define DIN0 128
#define NG 256
#define NEG 0.2f

#define SCHUNK 1024
#define SNB ((NN + SCHUNK - 1) / SCHUNK)   // 49 blocks

// ---- CSR build ----
__global__ void k_zero_int(int* __restrict__ p, int n) {
    int i = blockIdx.x * 256 + threadIdx.x;
    if (i < n) p[i] = 0;
}

__global__ void k_hist(const int* __restrict__ edst, int* __restrict__ cnt) {
    int e = blockIdx.x * 256 + threadIdx.x;
    if (e < NE) atomicAdd(&cnt[edst[e]], 1);
}

__global__ __launch_bounds__(256) void k_scan_part(const int* __restrict__ cnt,
                                                   int* __restrict__ part) {
    __shared__ int ws[4];
    int b = blockIdx.x, t = threadIdx.x;
    int i0 = b * SCHUNK + t * 4;
    int s = 0;
#pragma unroll
    for (int j = 0; j < 4; j++) {
        int i = i0 + j;
        if (i < NN) s += cnt[i];
    }
#pragma unroll
    for (int o = 32; o; o >>= 1) s += __shfl_xor(s, o, 64);
    if ((t & 63) == 0) ws[t >> 6] = s;
    __syncthreads();
    if (t == 0) part[b] = ws[0] + ws[1] + ws[2] + ws[3];
}

__global__ void k_scan_small(const int* __restrict__ part, int* __restrict__ partScan) {
    __shared__ int sh[SNB];
    int t = threadIdx.x;
    if (t < SNB) sh[t] = part[t];
    __syncthreads();
    if (t < SNB) {
        int s = 0;
        for (int i = 0; i < t; i++) s += sh[i];
        partScan[t] = s;
    }
}

__global__ __launch_bounds__(256) void k_scan_emit(const int* __restrict__ cnt,
                                                   const int* __restrict__ partScan,
                                                   int* __restrict__ off,
                                                   int* __restrict__ cursor) {
    __shared__ int tsum[256];
    int b = blockIdx.x, t = threadIdx.x;
    int i0 = b * SCHUNK + t * 4;
    int e[4], p[4];
    int s = 0;
#pragma unroll
    for (int j = 0; j < 4; j++) {
        int i = i0 + j;
        e[j] = (i < NN) ? cnt[i] : 0;
        p[j] = s;
        s += e[j];
    }
    tsum[t] = s;
    __syncthreads();
    for (int d = 1; d < 256; d <<= 1) {
        int v = (t >= d) ? tsum[t - d] : 0;
        __syncthreads();
        tsum[t] += v;
        __syncthreads();
    }
    int base = partScan[b] + ((t == 0) ? 0 : tsum[t - 1]);
#pragma unroll
    for (int j = 0; j < 4; j++) {
        int i = i0 + j;
        if (i < NN) {
            int v = base + p[j];
            off[i] = v; cursor[i] = v;
            if (i == NN - 1) off[NN] = v + e[j];
        }
    }
}

__global__ void k_scatter_ids(const int* __restrict__ esrc, const int* __restrict__ edst,
                              int* __restrict__ cursor, int* __restrict__ srcs) {
    int e = blockIdx.x * 256 + threadIdx.x;
    if (e >= NE) return;
    int pos = atomicAdd(&cursor[edst[e]], 1);
    srcs[pos] = esrc[e];
}

// ---- per-graph node range from sorted batch ----
__global__ void k_bounds(const int* __restrict__ batch,
                         int* __restrict__ startg, int* __restrict__ endg) {
    int i = blockIdx.x * 256 + threadIdx.x;
    if (i >= NN) return;
    int g = batch[i];
    if (i == 0 || batch[i - 1] != g) startg[g] = i;
    if (i == NN - 1 || batch[i + 1] != g) endg[g] = i + 1;
}

// ---- weight pre-transpose: Wt[m][k][c] = Wm[c][k] (HID=64 channels) ----
__global__ void k_wt(const float* __restrict__ Wl, const float* __restrict__ Wr,
                     const float* __restrict__ Rw, float* __restrict__ Wt, int din) {
    int i = blockIdx.x * 256 + threadIdx.x;
    if (i >= 3 * din * 64) return;
    int c = i & 63;
    int k = (i >> 6) & (din - 1);      // din is a power of 2 (128 or 64)
    int m = i / (din * 64);
    const float* Wm = (m == 0) ? Wl : (m == 1) ? Wr : Rw;
    Wt[i] = Wm[c * din + k];
}

// ---- fused node GEMMs: xl = x@Wl^T, xr = x@Wr^T, acc = x@Rw^T + Rb + b ----
// LDS tiles padded to stride 65 -> conflict-free staging and reads.
template <int DIN, bool RELU>
__global__ __launch_bounds__(256) void k_gemm(
        const float* __restrict__ xin, const float* __restrict__ Wt,
        const float* __restrict__ bvec, const float* __restrict__ rb,
        float* __restrict__ xl, float* __restrict__ xr, float* __restrict__ acc) {
    constexpr int KC = 64;
    constexpr int LDW = 65;
    __shared__ float xs[64 * LDW];        // 16.6 KB
    __shared__ float ws[3 * KC * LDW];    // 49.9 KB

    const int tid = threadIdx.x;
    const int cg = tid & 15;
    const int ng = tid >> 4;
    const int nb0 = blockIdx.x * 64;

    float4 al[4], ar[4], av[4];
#pragma unroll
    for (int i = 0; i < 4; i++) {
        al[i] = make_float4(0.f, 0.f, 0.f, 0.f);
        ar[i] = make_float4(0.f, 0.f, 0.f, 0.f);
        av[i] = make_float4(0.f, 0.f, 0.f, 0.f);
    }

    for (int c0 = 0; c0 < DIN; c0 += KC) {
        if (c0) __syncthreads();
        // x tile: 64 rows x 64 k -> b128 loads, b128 LDS writes (2-way = free)
        for (int q = tid; q < 64 * 16; q += 256) {
            int row = q >> 4, kq = q & 15;
            int n = nb0 + row;
            float4 v = make_float4(0.f, 0.f, 0.f, 0.f);
            if (n < NN) {
                v = *(const float4*)&xin[(size_t)n * DIN + c0 + 4 * kq];
                if (RELU) {
                    v.x = fmaxf(v.x, 0.f); v.y = fmaxf(v.y, 0.f);
                    v.z = fmaxf(v.z, 0.f); v.w = fmaxf(v.w, 0.f);
                }
            }
            *(float4*)&xs[row * LDW + 4 * kq] = v;
        }
        // W tiles: already k-major in Wt -> straight b128 copy
        for (int q = tid; q < 3 * 64 * 16; q += 256) {
            int m = q >> 10, r = q & 1023, kl = r >> 4, cq = r & 15;
            float4 v = *(const float4*)&Wt[(((size_t)m * DIN + c0 + kl) << 6) + 4 * cq];
            *(float4*)&ws[(m * KC + kl) * LDW + 4 * cq] = v;
        }
        __syncthreads();

#pragma unroll 8
        for (int k = 0; k < KC; k++) {
            float4 w0 = *(const float4*)&ws[(0 * KC + k) * LDW + 4 * cg];
            float4 w1 = *(const float4*)&ws[(1 * KC + k) * LDW + 4 * cg];
            float4 w2 = *(const float4*)&ws[(2 * KC + k) * LDW + 4 * cg];
            float xv[4];
            xv[0] = xs[(4 * ng + 0) * LDW + k];
            xv[1] = xs[(4 * ng + 1) * LDW + k];
            xv[2] = xs[(4 * ng + 2) * LDW + k];
            xv[3] = xs[(4 * ng + 3) * LDW + k];
#pragma unroll
            for (int i = 0; i < 4; i++) {
                float xi = xv[i];
                al[i].x += xi * w0.x; al[i].y += xi * w0.y; al[i].z += xi * w0.z; al[i].w += xi * w0.w;
                ar[i].x += xi * w1.x; ar[i].y += xi * w1.y; ar[i].z += xi * w1.z; ar[i].w += xi * w1.w;
                av[i].x += xi * w2.x; av[i].y += xi * w2.y; av[i].z += xi * w2.z; av[i].w += xi * w2.w;
            }
        }
    }

    float4 b4 = ((const float4*)bvec)[cg];
    float4 r4 = ((const float4*)rb)[cg];
#pragma unroll
    for (int i = 0; i < 4; i++) {
        int n = nb0 + 4 * ng + i;
        if (n < NN) {
            ((float4*)&xl[(size_t)n * HID])[cg] = al[i];
            ((float4*)&xr[(size_t)n * HID])[cg] = ar[i];
            float4 o = av[i];
            o.x += b4.x + r4.x; o.y += b4.y + r4.y;
            o.z += b4.z + r4.z; o.w += b4.w + r4.w;
            ((float4*)&acc[(size_t)n * HID])[cg] = o;
        }
    }
}

// ---- fused per-dst attention: 8 edges x 8 channels per wave ----
__global__ __launch_bounds__(256) void k_attn_dst(
        const int* __restrict__ off, const int* __restrict__ srcs,
        const float* __restrict__ xl, const float* __restrict__ xr,
        const float* __restrict__ att, float* __restrict__ acc) {
    const int lane = threadIdx.x & 63;
    const int d = blockIdx.x * 4 + (threadIdx.x >> 6);
    if (d >= NN) return;
    const int e = lane >> 3;
    const int cg = lane & 7;

    const float4* xr4 = (const float4*)&xr[(size_t)d * HID + 8 * cg];
    float4 xra = xr4[0], xrb = xr4[1];
    const float4* at4 = (const float4*)&att[8 * cg];
    float4 ata = at4[0], atb = at4[1];

#define EDGE_LOGIT(S, XA, XB, T)                                               \
    {                                                                          \
        const float4* _x4 = (const float4*)&xl[(size_t)(S) * HID + 8 * cg];    \
        XA = _x4[0]; XB = _x4[1];                                              \
        float _ps;                                                             \
        float _v;                                                              \
        _v = XA.x + xra.x; _ps  = (fmaxf(_v,0.f) + NEG*fminf(_v,0.f)) * ata.x; \
        _v = XA.y + xra.y; _ps += (fmaxf(_v,0.f) + NEG*fminf(_v,0.f)) * ata.y; \
        _v = XA.z + xra.z; _ps += (fmaxf(_v,0.f) + NEG*fminf(_v,0.f)) * ata.z; \
        _v = XA.w + xra.w; _ps += (fmaxf(_v,0.f) + NEG*fminf(_v,0.f)) * ata.w; \
        _v = XB.x + xrb.x; _ps += (fmaxf(_v,0.f) + NEG*fminf(_v,0.f)) * atb.x; \
        _v = XB.y + xrb.y; _ps += (fmaxf(_v,0.f) + NEG*fminf(_v,0.f)) * atb.y; \
        _v = XB.z + xrb.z; _ps += (fmaxf(_v,0.f) + NEG*fminf(_v,0.f)) * atb.z; \
        _v = XB.w + xrb.w; _ps += (fmaxf(_v,0.f) + NEG*fminf(_v,0.f)) * atb.w; \
        _ps += __shfl_xor(_ps, 1, 64);                                         \
        _ps += __shfl_xor(_ps, 2, 64);                                         \
        _ps += __shfl_xor(_ps, 4, 64);                                         \
        T = _ps;                                                               \
    }

    float m, l;
    float4 oA, oB;
    {
        float4 xla, xlb; float t;
        EDGE_LOGIT(d, xla, xlb, t);
        m = t;
        bool own = (e == 0);
        l = own ? 1.f : 0.f;
        oA = own ? xla : make_float4(0.f, 0.f, 0.f, 0.f);
        oB = own ? xlb : make_float4(0.f, 0.f, 0.f, 0.f);
    }

    const int lo = off[d], deg = off[d + 1] - lo;
    for (int base = 0; base < deg; base += 8) {
        int nv = deg - base;
        int sv = 0;
        if (lane < 8) sv = srcs[lo + min(base + lane, deg - 1)];
        int s = __shfl(sv, e, 64);

        float4 xla, xlb; float t;
        EDGE_LOGIT(s, xla, xlb, t);
        if (e >= nv) t = -INFINITY;

        float cm = t;
        cm = fmaxf(cm, __shfl_xor(cm, 8, 64));
        cm = fmaxf(cm, __shfl_xor(cm, 16, 64));
        cm = fmaxf(cm, __shfl_xor(cm, 32, 64));
        float newm = fmaxf(m, cm);
        float corr = __expf(m - newm);
        float p = __expf(t - newm);
        m = newm;
        l = l * corr + p;
        oA.x = oA.x * corr + p * xla.x; oA.y = oA.y * corr + p * xla.y;
        oA.z = oA.z * corr + p * xla.z; oA.w = oA.w * corr + p * xla.w;
        oB.x = oB.x * corr + p * xlb.x; oB.y = oB.y * corr + p * xlb.y;
        oB.z = oB.z * corr + p * xlb.z; oB.w = oB.w * corr + p * xlb.w;
    }
#undef EDGE_LOGIT

#pragma unroll
    for (int w = 8; w <= 32; w <<= 1) {
        l    += __shfl_xor(l, w, 64);
        oA.x += __shfl_xor(oA.x, w, 64); oA.y += __shfl_xor(oA.y, w, 64);
        oA.z += __shfl_xor(oA.z, w, 64); oA.w += __shfl_xor(oA.w, w, 64);
        oB.x += __shfl_xor(oB.x, w, 64); oB.y += __shfl_xor(oB.y, w, 64);
        oB.z += __shfl_xor(oB.z, w, 64); oB.w += __shfl_xor(oB.w, w, 64);
    }

    if (e == 0) {
        float inv = 1.f / l;
        float4* a4 = (float4*)&acc[(size_t)d * HID + 8 * cg];
        float4 c0 = a4[0], c1 = a4[1];
        c0.x += oA.x * inv; c0.y += oA.y * inv;
        c0.z += oA.z * inv; c0.w += oA.w * inv;
        c1.x += oB.x * inv; c1.y += oB.y * inv;
        c1.z += oB.z * inv; c1.w += oB.w * inv;
        a4[0] = c0; a4[1] = c1;
    }
}

// ---- fused mean-pool + head: one block (512 thr) per graph ----
__global__ __launch_bounds__(512) void k_pool_final(
        const float* __restrict__ acc,
        const int* __restrict__ startg, const int* __restrict__ endg,
        const float* __restrict__ Wf, const float* __restrict__ bf_,
        float* __restrict__ out) {
    __shared__ float red[8][HID];
    const int g = blockIdx.x;
    const int c = threadIdx.x & 63;
    const int j = threadIdx.x >> 6;
    const int s = startg[g], epos = endg[g];

    float sum = 0.f;
    for (int n = s + j; n < epos; n += 8)
        sum += acc[(size_t)n * HID + c];
    red[j][c] = sum;
    __syncthreads();

    if (threadIdx.x < HID) {
        float tot = 0.f;
#pragma unroll
        for (int w = 0; w < 8; w++) tot += red[w][c];
        float cntf = (float)(epos - s);
        float v = tot / fmaxf(cntf, 1.f) * Wf[c];
#pragma unroll
        for (int o = 32; o; o >>= 1) v += __shfl_xor(v, o, 64);
        if (c == 0) out[g] = v + bf_[0];
    }
}

extern "C" void kernel_launch(void* const* d_in, const int* in_sizes, int n_in,
                              void* d_out, int out_size, void* d_ws, size_t ws_size,
                              hipStream_t stream) {
    const float* x   = (const float*)d_in[0];
    const int* eidx  = (const int*)d_in[1];
    const int* batch = (const int*)d_in[2];
    const int* esrc = eidx;
    const int* edst = eidx + NE;
    const float* Wf  = (const float*)d_in[21];
    const float* bfb = (const float*)d_in[22];

    float* wsf = (float*)d_ws;
    const size_t NN64 = (size_t)NN * HID;
    float* xl     = wsf;
    float* xr     = xl + NN64;
    float* acc0   = xr + NN64;
    float* acc1   = acc0 + NN64;
    int*   ccnt   = (int*)(acc1 + NN64);
    int*   startg = ccnt + NN;
    int*   endg   = startg + NG;
    int*   off    = endg + NG;
    int*   cursor = off + NN + 1;
    int*   part   = cursor + NN;
    int*   partSc = part + SNB;
    int*   srcs   = partSc + SNB;
    float* Wt0    = (float*)(srcs + NE);
    float* Wt1    = Wt0 + 3 * DIN0 * HID;
    float* Wt2    = Wt1 + 3 * HID * HID;
    float* Wts[3] = {Wt0, Wt1, Wt2};

    // weight pre-transpose (tiny) + CSR build + graph bounds
    k_wt<<<(3 * DIN0 * HID + 255) / 256, 256, 0, stream>>>(
        (const float*)d_in[3], (const float*)d_in[4], (const float*)d_in[7], Wt0, DIN0);
    k_wt<<<(3 * HID * HID + 255) / 256, 256, 0, stream>>>(
        (const float*)d_in[9], (const float*)d_in[10], (const float*)d_in[13], Wt1, HID);
    k_wt<<<(3 * HID * HID + 255) / 256, 256, 0, stream>>>(
        (const float*)d_in[15], (const float*)d_in[16], (const float*)d_in[19], Wt2, HID);

    k_zero_int<<<(NN + 2 * NG + 255) / 256, 256, 0, stream>>>(ccnt, NN + 2 * NG);
    k_hist<<<(NE + 255) / 256, 256, 0, stream>>>(edst, ccnt);
    k_scan_part<<<SNB, 256, 0, stream>>>(ccnt, part);
    k_scan_small<<<1, 64, 0, stream>>>(part, partSc);
    k_scan_emit<<<SNB, 256, 0, stream>>>(ccnt, partSc, off, cursor);
    k_scatter_ids<<<(NE + 255) / 256, 256, 0, stream>>>(esrc, edst, cursor, srcs);
    k_bounds<<<(NN + 255) / 256, 256, 0, stream>>>(batch, startg, endg);

    float* accs[4] = {acc0, acc0, acc1, acc0};  // out of layer L = accs[L+1]
    const int gemm_grid = (NN + 63) / 64;
    for (int L = 0; L < 3; L++) {
        const float* att = (const float*)d_in[3 + L * 6 + 2];
        const float* b   = (const float*)d_in[3 + L * 6 + 3];
        const float* Rb  = (const float*)d_in[3 + L * 6 + 5];
        float* accOut = accs[L + 1];

        if (L == 0)
            k_gemm<DIN0, false><<<gemm_grid, 256, 0, stream>>>(
                x, Wts[0], b, Rb, xl, xr, accOut);
        else
            k_gemm<HID, true><<<gemm_grid, 256, 0, stream>>>(
                accs[L], Wts[L], b, Rb, xl, xr, accOut);

        k_attn_dst<<<(NN + 3) / 4, 256, 0, stream>>>(off, srcs, xl, xr, att, accOut);
    }

    k_pool_final<<<NG, 512, 0, stream>>>(accs[3], startg, endg, Wf, bfb, (float*)d_out);
}

// Round 10
// 477.625 us; speedup vs baseline: 1.0866x; 1.0866x over previous
//
#include <hip/hip_runtime.h>

// GATv2 3-layer + mean-pool + linear head, MI355X.
// R9: (1) gemm v3 — 4ch x 8node micro-tile, BN=128/KC=32, 41KB LDS
//     (2.4 FLOP per LDS byte; was 1.5 — gemm is LDS-BW-bound, not
//     conflict-bound as R8 assumed).
//     (2) k_scatter_ids partitioned into 8 dst-ranges with XCD-affine
//     blockIdx swizzle — srcs writes stay in one XCD's L2 (was 67MB of
//     cross-XCD dirty-line writebacks for 4MB of payload).

#define NN 50000
#define NE 1000000
#define HID 64
#define DIN0 128
#define NG 256
#define NEG 0.2f

#define SCHUNK 1024
#define SNB ((NN + SCHUNK - 1) / SCHUNK)   // 49 blocks

// ---- CSR build ----
__global__ void k_zero_int(int* __restrict__ p, int n) {
    int i = blockIdx.x * 256 + threadIdx.x;
    if (i < n) p[i] = 0;
}

__global__ void k_hist(const int* __restrict__ edst, int* __restrict__ cnt) {
    int e = blockIdx.x * 256 + threadIdx.x;
    if (e < NE) atomicAdd(&cnt[edst[e]], 1);
}

__global__ __launch_bounds__(256) void k_scan_part(const int* __restrict__ cnt,
                                                   int* __restrict__ part) {
    __shared__ int ws[4];
    int b = blockIdx.x, t = threadIdx.x;
    int i0 = b * SCHUNK + t * 4;
    int s = 0;
#pragma unroll
    for (int j = 0; j < 4; j++) {
        int i = i0 + j;
        if (i < NN) s += cnt[i];
    }
#pragma unroll
    for (int o = 32; o; o >>= 1) s += __shfl_xor(s, o, 64);
    if ((t & 63) == 0) ws[t >> 6] = s;
    __syncthreads();
    if (t == 0) part[b] = ws[0] + ws[1] + ws[2] + ws[3];
}

__global__ void k_scan_small(const int* __restrict__ part, int* __restrict__ partScan) {
    __shared__ int sh[SNB];
    int t = threadIdx.x;
    if (t < SNB) sh[t] = part[t];
    __syncthreads();
    if (t < SNB) {
        int s = 0;
        for (int i = 0; i < t; i++) s += sh[i];
        partScan[t] = s;
    }
}

__global__ __launch_bounds__(256) void k_scan_emit(const int* __restrict__ cnt,
                                                   const int* __restrict__ partScan,
                                                   int* __restrict__ off,
                                                   int* __restrict__ cursor) {
    __shared__ int tsum[256];
    int b = blockIdx.x, t = threadIdx.x;
    int i0 = b * SCHUNK + t * 4;
    int e[4], p[4];
    int s = 0;
#pragma unroll
    for (int j = 0; j < 4; j++) {
        int i = i0 + j;
        e[j] = (i < NN) ? cnt[i] : 0;
        p[j] = s;
        s += e[j];
    }
    tsum[t] = s;
    __syncthreads();
    for (int d = 1; d < 256; d <<= 1) {
        int v = (t >= d) ? tsum[t - d] : 0;
        __syncthreads();
        tsum[t] += v;
        __syncthreads();
    }
    int base = partScan[b] + ((t == 0) ? 0 : tsum[t - 1]);
#pragma unroll
    for (int j = 0; j < 4; j++) {
        int i = i0 + j;
        if (i < NN) {
            int v = base + p[j];
            off[i] = v; cursor[i] = v;
            if (i == NN - 1) off[NN] = v + e[j];
        }
    }
}

// 8 dst-range groups; group = blockIdx&7 (XCD-affine). Each group streams the
// full edge list, scatters only its dst range -> writes localized to one L2.
#define SCAT_BPG 96
__global__ __launch_bounds__(256) void k_scatter_ids(
        const int* __restrict__ esrc, const int* __restrict__ edst,
        int* __restrict__ cursor, int* __restrict__ srcs) {
    const int grp = blockIdx.x & 7;
    const int blk = blockIdx.x >> 3;
    const int dlo = grp * (NN / 8), dhi = dlo + (NN / 8);
    for (int e = blk * 256 + threadIdx.x; e < NE; e += SCAT_BPG * 256) {
        int d = edst[e];
        if (d >= dlo && d < dhi) {
            int pos = atomicAdd(&cursor[d], 1);
            srcs[pos] = esrc[e];
        }
    }
}

// ---- per-graph node range from sorted batch ----
__global__ void k_bounds(const int* __restrict__ batch,
                         int* __restrict__ startg, int* __restrict__ endg) {
    int i = blockIdx.x * 256 + threadIdx.x;
    if (i >= NN) return;
    int g = batch[i];
    if (i == 0 || batch[i - 1] != g) startg[g] = i;
    if (i == NN - 1 || batch[i + 1] != g) endg[g] = i + 1;
}

// ---- weight pre-transpose: Wt[m][k][c] = Wm[c][k] ----
__global__ void k_wt(const float* __restrict__ Wl, const float* __restrict__ Wr,
                     const float* __restrict__ Rw, float* __restrict__ Wt, int din) {
    int i = blockIdx.x * 256 + threadIdx.x;
    if (i >= 3 * din * 64) return;
    int c = i & 63;
    int k = (i >> 6) & (din - 1);
    int m = i / (din * 64);
    const float* Wm = (m == 0) ? Wl : (m == 1) ? Wr : Rw;
    Wt[i] = Wm[c * din + k];
}

// ---- fused node GEMMs: xl = x@Wl^T, xr = x@Wr^T, acc = x@Rw^T + Rb + b ----
// BN=128 nodes, KC=32, 256 threads, micro-tile 4 channels x 8 nodes.
template <int DIN, bool RELU>
__global__ __launch_bounds__(256, 3) void k_gemm(
        const float* __restrict__ xin, const float* __restrict__ Wt,
        const float* __restrict__ bvec, const float* __restrict__ rb,
        float* __restrict__ xl, float* __restrict__ xr, float* __restrict__ acc) {
    constexpr int KC = 32;
    constexpr int LDX = KC + 1;            // 33
    __shared__ float xs[128 * LDX];        // 16.9 KB
    __shared__ float ws3[3 * KC * 64];     // 24 KB

    const int tid = threadIdx.x;
    const int cg = tid & 15;               // channels 4cg..4cg+3
    const int ng = tid >> 4;               // nodes 8ng..8ng+7
    const int nb0 = blockIdx.x * 128;

    float4 al[8], ar[8], av[8];
#pragma unroll
    for (int i = 0; i < 8; i++) {
        al[i] = make_float4(0.f, 0.f, 0.f, 0.f);
        ar[i] = make_float4(0.f, 0.f, 0.f, 0.f);
        av[i] = make_float4(0.f, 0.f, 0.f, 0.f);
    }

    for (int c0 = 0; c0 < DIN; c0 += KC) {
        if (c0) __syncthreads();
        // x tile: 128 rows x 32 k (8 float4/row) = 1024 float4, 4 per thread
        for (int q = tid; q < 128 * 8; q += 256) {
            int row = q >> 3, kq = q & 7;
            int n = nb0 + row;
            float4 v = make_float4(0.f, 0.f, 0.f, 0.f);
            if (n < NN) {
                v = *(const float4*)&xin[(size_t)n * DIN + c0 + 4 * kq];
                if (RELU) {
                    v.x = fmaxf(v.x, 0.f); v.y = fmaxf(v.y, 0.f);
                    v.z = fmaxf(v.z, 0.f); v.w = fmaxf(v.w, 0.f);
                }
            }
            *(float4*)&xs[row * LDX + 4 * kq] = v;
        }
        // W tiles: 3 x 32 k x 64 c = 1536 float4, 6 per thread
        for (int q = tid; q < 3 * KC * 16; q += 256) {
            int m = q >> 9, r = q & 511, kl = r >> 4, cq = r & 15;
            float4 v = *(const float4*)&Wt[(((size_t)m * DIN + c0 + kl) << 6) + 4 * cq];
            *(float4*)&ws3[(m * KC + kl) * 64 + 4 * cq] = v;
        }
        __syncthreads();

#pragma unroll 4
        for (int k = 0; k < KC; k++) {
            float4 w0 = *(const float4*)&ws3[(0 * KC + k) * 64 + 4 * cg];
            float4 w1 = *(const float4*)&ws3[(1 * KC + k) * 64 + 4 * cg];
            float4 w2 = *(const float4*)&ws3[(2 * KC + k) * 64 + 4 * cg];
#pragma unroll
            for (int i = 0; i < 8; i++) {
                float xi = xs[(8 * ng + i) * LDX + k];
                al[i].x += xi * w0.x; al[i].y += xi * w0.y; al[i].z += xi * w0.z; al[i].w += xi * w0.w;
                ar[i].x += xi * w1.x; ar[i].y += xi * w1.y; ar[i].z += xi * w1.z; ar[i].w += xi * w1.w;
                av[i].x += xi * w2.x; av[i].y += xi * w2.y; av[i].z += xi * w2.z; av[i].w += xi * w2.w;
            }
        }
    }

    float4 b4 = ((const float4*)bvec)[cg];
    float4 r4 = ((const float4*)rb)[cg];
#pragma unroll
    for (int i = 0; i < 8; i++) {
        int n = nb0 + 8 * ng + i;
        if (n < NN) {
            ((float4*)&xl[(size_t)n * HID])[cg] = al[i];
            ((float4*)&xr[(size_t)n * HID])[cg] = ar[i];
            float4 o = av[i];
            o.x += b4.x + r4.x; o.y += b4.y + r4.y;
            o.z += b4.z + r4.z; o.w += b4.w + r4.w;
            ((float4*)&acc[(size_t)n * HID])[cg] = o;
        }
    }
}

// ---- fused per-dst attention: 8 edges x 8 channels per wave ----
__global__ __launch_bounds__(256) void k_attn_dst(
        const int* __restrict__ off, const int* __restrict__ srcs,
        const float* __restrict__ xl, const float* __restrict__ xr,
        const float* __restrict__ att, float* __restrict__ acc) {
    const int lane = threadIdx.x & 63;
    const int d = blockIdx.x * 4 + (threadIdx.x >> 6);
    if (d >= NN) return;
    const int e = lane >> 3;
    const int cg = lane & 7;

    const float4* xr4 = (const float4*)&xr[(size_t)d * HID + 8 * cg];
    float4 xra = xr4[0], xrb = xr4[1];
    const float4* at4 = (const float4*)&att[8 * cg];
    float4 ata = at4[0], atb = at4[1];

#define EDGE_LOGIT(S, XA, XB, T)                                               \
    {                                                                          \
        const float4* _x4 = (const float4*)&xl[(size_t)(S) * HID + 8 * cg];    \
        XA = _x4[0]; XB = _x4[1];                                              \
        float _ps;                                                             \
        float _v;                                                              \
        _v = XA.x + xra.x; _ps  = (fmaxf(_v,0.f) + NEG*fminf(_v,0.f)) * ata.x; \
        _v = XA.y + xra.y; _ps += (fmaxf(_v,0.f) + NEG*fminf(_v,0.f)) * ata.y; \
        _v = XA.z + xra.z; _ps += (fmaxf(_v,0.f) + NEG*fminf(_v,0.f)) * ata.z; \
        _v = XA.w + xra.w; _ps += (fmaxf(_v,0.f) + NEG*fminf(_v,0.f)) * ata.w; \
        _v = XB.x + xrb.x; _ps += (fmaxf(_v,0.f) + NEG*fminf(_v,0.f)) * atb.x; \
        _v = XB.y + xrb.y; _ps += (fmaxf(_v,0.f) + NEG*fminf(_v,0.f)) * atb.y; \
        _v = XB.z + xrb.z; _ps += (fmaxf(_v,0.f) + NEG*fminf(_v,0.f)) * atb.z; \
        _v = XB.w + xrb.w; _ps += (fmaxf(_v,0.f) + NEG*fminf(_v,0.f)) * atb.w; \
        _ps += __shfl_xor(_ps, 1, 64);                                         \
        _ps += __shfl_xor(_ps, 2, 64);                                         \
        _ps += __shfl_xor(_ps, 4, 64);                                         \
        T = _ps;                                                               \
    }

    float m, l;
    float4 oA, oB;
    {
        float4 xla, xlb; float t;
        EDGE_LOGIT(d, xla, xlb, t);
        m = t;
        bool own = (e == 0);
        l = own ? 1.f : 0.f;
        oA = own ? xla : make_float4(0.f, 0.f, 0.f, 0.f);
        oB = own ? xlb : make_float4(0.f, 0.f, 0.f, 0.f);
    }

    const int lo = off[d], deg = off[d + 1] - lo;
    for (int base = 0; base < deg; base += 8) {
        int nv = deg - base;
        int sv = 0;
        if (lane < 8) sv = srcs[lo + min(base + lane, deg - 1)];
        int s = __shfl(sv, e, 64);

        float4 xla, xlb; float t;
        EDGE_LOGIT(s, xla, xlb, t);
        if (e >= nv) t = -INFINITY;

        float cm = t;
        cm = fmaxf(cm, __shfl_xor(cm, 8, 64));
        cm = fmaxf(cm, __shfl_xor(cm, 16, 64));
        cm = fmaxf(cm, __shfl_xor(cm, 32, 64));
        float newm = fmaxf(m, cm);
        float corr = __expf(m - newm);
        float p = __expf(t - newm);
        m = newm;
        l = l * corr + p;
        oA.x = oA.x * corr + p * xla.x; oA.y = oA.y * corr + p * xla.y;
        oA.z = oA.z * corr + p * xla.z; oA.w = oA.w * corr + p * xla.w;
        oB.x = oB.x * corr + p * xlb.x; oB.y = oB.y * corr + p * xlb.y;
        oB.z = oB.z * corr + p * xlb.z; oB.w = oB.w * corr + p * xlb.w;
    }
#undef EDGE_LOGIT

#pragma unroll
    for (int w = 8; w <= 32; w <<= 1) {
        l    += __shfl_xor(l, w, 64);
        oA.x += __shfl_xor(oA.x, w, 64); oA.y += __shfl_xor(oA.y, w, 64);
        oA.z += __shfl_xor(oA.z, w, 64); oA.w += __shfl_xor(oA.w, w, 64);
        oB.x += __shfl_xor(oB.x, w, 64); oB.y += __shfl_xor(oB.y, w, 64);
        oB.z += __shfl_xor(oB.z, w, 64); oB.w += __shfl_xor(oB.w, w, 64);
    }

    if (e == 0) {
        float inv = 1.f / l;
        float4* a4 = (float4*)&acc[(size_t)d * HID + 8 * cg];
        float4 c0 = a4[0], c1 = a4[1];
        c0.x += oA.x * inv; c0.y += oA.y * inv;
        c0.z += oA.z * inv; c0.w += oA.w * inv;
        c1.x += oB.x * inv; c1.y += oB.y * inv;
        c1.z += oB.z * inv; c1.w += oB.w * inv;
        a4[0] = c0; a4[1] = c1;
    }
}

// ---- fused mean-pool + head: one block (512 thr) per graph ----
__global__ __launch_bounds__(512) void k_pool_final(
        const float* __restrict__ acc,
        const int* __restrict__ startg, const int* __restrict__ endg,
        const float* __restrict__ Wf, const float* __restrict__ bf_,
        float* __restrict__ out) {
    __shared__ float red[8][HID];
    const int g = blockIdx.x;
    const int c = threadIdx.x & 63;
    const int j = threadIdx.x >> 6;
    const int s = startg[g], epos = endg[g];

    float sum = 0.f;
    for (int n = s + j; n < epos; n += 8)
        sum += acc[(size_t)n * HID + c];
    red[j][c] = sum;
    __syncthreads();

    if (threadIdx.x < HID) {
        float tot = 0.f;
#pragma unroll
        for (int w = 0; w < 8; w++) tot += red[w][c];
        float cntf = (float)(epos - s);
        float v = tot / fmaxf(cntf, 1.f) * Wf[c];
#pragma unroll
        for (int o = 32; o; o >>= 1) v += __shfl_xor(v, o, 64);
        if (c == 0) out[g] = v + bf_[0];
    }
}

extern "C" void kernel_launch(void* const* d_in, const int* in_sizes, int n_in,
                              void* d_out, int out_size, void* d_ws, size_t ws_size,
                              hipStream_t stream) {
    const float* x   = (const float*)d_in[0];
    const int* eidx  = (const int*)d_in[1];
    const int* batch = (const int*)d_in[2];
    const int* esrc = eidx;
    const int* edst = eidx + NE;
    const float* Wf  = (const float*)d_in[21];
    const float* bfb = (const float*)d_in[22];

    float* wsf = (float*)d_ws;
    const size_t NN64 = (size_t)NN * HID;
    float* xl     = wsf;
    float* xr     = xl + NN64;
    float* acc0   = xr + NN64;
    float* acc1   = acc0 + NN64;
    int*   ccnt   = (int*)(acc1 + NN64);
    int*   startg = ccnt + NN;
    int*   endg   = startg + NG;
    int*   off    = endg + NG;
    int*   cursor = off + NN + 1;
    int*   part   = cursor + NN;
    int*   partSc = part + SNB;
    int*   srcs   = partSc + SNB;
    float* Wt0    = (float*)(srcs + NE);
    float* Wt1    = Wt0 + 3 * DIN0 * HID;
    float* Wt2    = Wt1 + 3 * HID * HID;
    float* Wts[3] = {Wt0, Wt1, Wt2};

    // weight pre-transpose (tiny) + CSR build + graph bounds
    k_wt<<<(3 * DIN0 * HID + 255) / 256, 256, 0, stream>>>(
        (const float*)d_in[3], (const float*)d_in[4], (const float*)d_in[7], Wt0, DIN0);
    k_wt<<<(3 * HID * HID + 255) / 256, 256, 0, stream>>>(
        (const float*)d_in[9], (const float*)d_in[10], (const float*)d_in[13], Wt1, HID);
    k_wt<<<(3 * HID * HID + 255) / 256, 256, 0, stream>>>(
        (const float*)d_in[15], (const float*)d_in[16], (const float*)d_in[19], Wt2, HID);

    k_zero_int<<<(NN + 2 * NG + 255) / 256, 256, 0, stream>>>(ccnt, NN + 2 * NG);
    k_hist<<<(NE + 255) / 256, 256, 0, stream>>>(edst, ccnt);
    k_scan_part<<<SNB, 256, 0, stream>>>(ccnt, part);
    k_scan_small<<<1, 64, 0, stream>>>(part, partSc);
    k_scan_emit<<<SNB, 256, 0, stream>>>(ccnt, partSc, off, cursor);
    k_scatter_ids<<<8 * SCAT_BPG, 256, 0, stream>>>(esrc, edst, cursor, srcs);
    k_bounds<<<(NN + 255) / 256, 256, 0, stream>>>(batch, startg, endg);

    float* accs[4] = {acc0, acc0, acc1, acc0};  // out of layer L = accs[L+1]
    const int gemm_grid = (NN + 127) / 128;
    for (int L = 0; L < 3; L++) {
        const float* att = (const float*)d_in[3 + L * 6 + 2];
        const float* b   = (const float*)d_in[3 + L * 6 + 3];
        const float* Rb  = (const float*)d_in[3 + L * 6 + 5];
        float* accOut = accs[L + 1];

        if (L == 0)
            k_gemm<DIN0, false><<<gemm_grid, 256, 0, stream>>>(
                x, Wts[0], b, Rb, xl, xr, accOut);
        else
            k_gemm<HID, true><<<gemm_grid, 256, 0, stream>>>(
                accs[L], Wts[L], b, Rb, xl, xr, accOut);

        k_attn_dst<<<(NN + 3) / 4, 256, 0, stream>>>(off, srcs, xl, xr, att, accOut);
    }

    k_pool_final<<<NG, 512, 0, stream>>>(accs[3], startg, endg, Wf, bfb, (float*)d_out);
}

// Round 11
// 460.308 us; speedup vs baseline: 1.1275x; 1.0376x over previous
//
#include <hip/hip_runtime.h>

// GATv2 3-layer + mean-pool + linear head, MI355X.
// R10: gemm v4 — BN=64 (grid 782 = ~3 blk/CU; was 391 = 1.5 blk/CU at 12%
// occupancy, pure latency starvation), micro 4ch x 4node, KC=32, 32.4KB LDS,
// __launch_bounds__(256,4).

#define NN 50000
#define NE 1000000
#define HID 64
#define DIN0 128
#define NG 256
#define NEG 0.2f

#define SCHUNK 1024
#define SNB ((NN + SCHUNK - 1) / SCHUNK)   // 49 blocks

// ---- CSR build ----
__global__ void k_zero_int(int* __restrict__ p, int n) {
    int i = blockIdx.x * 256 + threadIdx.x;
    if (i < n) p[i] = 0;
}

__global__ void k_hist(const int* __restrict__ edst, int* __restrict__ cnt) {
    int e = blockIdx.x * 256 + threadIdx.x;
    if (e < NE) atomicAdd(&cnt[edst[e]], 1);
}

__global__ __launch_bounds__(256) void k_scan_part(const int* __restrict__ cnt,
                                                   int* __restrict__ part) {
    __shared__ int ws[4];
    int b = blockIdx.x, t = threadIdx.x;
    int i0 = b * SCHUNK + t * 4;
    int s = 0;
#pragma unroll
    for (int j = 0; j < 4; j++) {
        int i = i0 + j;
        if (i < NN) s += cnt[i];
    }
#pragma unroll
    for (int o = 32; o; o >>= 1) s += __shfl_xor(s, o, 64);
    if ((t & 63) == 0) ws[t >> 6] = s;
    __syncthreads();
    if (t == 0) part[b] = ws[0] + ws[1] + ws[2] + ws[3];
}

__global__ void k_scan_small(const int* __restrict__ part, int* __restrict__ partScan) {
    __shared__ int sh[SNB];
    int t = threadIdx.x;
    if (t < SNB) sh[t] = part[t];
    __syncthreads();
    if (t < SNB) {
        int s = 0;
        for (int i = 0; i < t; i++) s += sh[i];
        partScan[t] = s;
    }
}

__global__ __launch_bounds__(256) void k_scan_emit(const int* __restrict__ cnt,
                                                   const int* __restrict__ partScan,
                                                   int* __restrict__ off,
                                                   int* __restrict__ cursor) {
    __shared__ int tsum[256];
    int b = blockIdx.x, t = threadIdx.x;
    int i0 = b * SCHUNK + t * 4;
    int e[4], p[4];
    int s = 0;
#pragma unroll
    for (int j = 0; j < 4; j++) {
        int i = i0 + j;
        e[j] = (i < NN) ? cnt[i] : 0;
        p[j] = s;
        s += e[j];
    }
    tsum[t] = s;
    __syncthreads();
    for (int d = 1; d < 256; d <<= 1) {
        int v = (t >= d) ? tsum[t - d] : 0;
        __syncthreads();
        tsum[t] += v;
        __syncthreads();
    }
    int base = partScan[b] + ((t == 0) ? 0 : tsum[t - 1]);
#pragma unroll
    for (int j = 0; j < 4; j++) {
        int i = i0 + j;
        if (i < NN) {
            int v = base + p[j];
            off[i] = v; cursor[i] = v;
            if (i == NN - 1) off[NN] = v + e[j];
        }
    }
}

// 8 dst-range groups; group = blockIdx&7 (XCD-affine).
#define SCAT_BPG 96
__global__ __launch_bounds__(256) void k_scatter_ids(
        const int* __restrict__ esrc, const int* __restrict__ edst,
        int* __restrict__ cursor, int* __restrict__ srcs) {
    const int grp = blockIdx.x & 7;
    const int blk = blockIdx.x >> 3;
    const int dlo = grp * (NN / 8), dhi = dlo + (NN / 8);
    for (int e = blk * 256 + threadIdx.x; e < NE; e += SCAT_BPG * 256) {
        int d = edst[e];
        if (d >= dlo && d < dhi) {
            int pos = atomicAdd(&cursor[d], 1);
            srcs[pos] = esrc[e];
        }
    }
}

// ---- per-graph node range from sorted batch ----
__global__ void k_bounds(const int* __restrict__ batch,
                         int* __restrict__ startg, int* __restrict__ endg) {
    int i = blockIdx.x * 256 + threadIdx.x;
    if (i >= NN) return;
    int g = batch[i];
    if (i == 0 || batch[i - 1] != g) startg[g] = i;
    if (i == NN - 1 || batch[i + 1] != g) endg[g] = i + 1;
}

// ---- weight pre-transpose: Wt[m][k][c] = Wm[c][k] ----
__global__ void k_wt(const float* __restrict__ Wl, const float* __restrict__ Wr,
                     const float* __restrict__ Rw, float* __restrict__ Wt, int din) {
    int i = blockIdx.x * 256 + threadIdx.x;
    if (i >= 3 * din * 64) return;
    int c = i & 63;
    int k = (i >> 6) & (din - 1);
    int m = i / (din * 64);
    const float* Wm = (m == 0) ? Wl : (m == 1) ? Wr : Rw;
    Wt[i] = Wm[c * din + k];
}

// ---- fused node GEMMs: xl = x@Wl^T, xr = x@Wr^T, acc = x@Rw^T + Rb + b ----
// BN=64 nodes, KC=32, 256 threads, micro-tile 4 channels x 4 nodes.
template <int DIN, bool RELU>
__global__ __launch_bounds__(256, 4) void k_gemm(
        const float* __restrict__ xin, const float* __restrict__ Wt,
        const float* __restrict__ bvec, const float* __restrict__ rb,
        float* __restrict__ xl, float* __restrict__ xr, float* __restrict__ acc) {
    constexpr int KC = 32;
    constexpr int LDX = KC + 1;            // 33
    __shared__ float xs[64 * LDX];         // 8.4 KB
    __shared__ float ws3[3 * KC * 64];     // 24 KB

    const int tid = threadIdx.x;
    const int cg = tid & 15;               // channels 4cg..4cg+3
    const int ng = tid >> 4;               // nodes 4ng..4ng+3
    const int nb0 = blockIdx.x * 64;

    float4 al[4], ar[4], av[4];
#pragma unroll
    for (int i = 0; i < 4; i++) {
        al[i] = make_float4(0.f, 0.f, 0.f, 0.f);
        ar[i] = make_float4(0.f, 0.f, 0.f, 0.f);
        av[i] = make_float4(0.f, 0.f, 0.f, 0.f);
    }

    for (int c0 = 0; c0 < DIN; c0 += KC) {
        if (c0) __syncthreads();
        // x tile: 64 rows x 32 k = 512 float4, 2 per thread
        for (int q = tid; q < 64 * 8; q += 256) {
            int row = q >> 3, kq = q & 7;
            int n = nb0 + row;
            float4 v = make_float4(0.f, 0.f, 0.f, 0.f);
            if (n < NN) {
                v = *(const float4*)&xin[(size_t)n * DIN + c0 + 4 * kq];
                if (RELU) {
                    v.x = fmaxf(v.x, 0.f); v.y = fmaxf(v.y, 0.f);
                    v.z = fmaxf(v.z, 0.f); v.w = fmaxf(v.w, 0.f);
                }
            }
            *(float4*)&xs[row * LDX + 4 * kq] = v;
        }
        // W tiles: 3 x 32 k x 64 c = 1536 float4, 6 per thread
        for (int q = tid; q < 3 * KC * 16; q += 256) {
            int m = q >> 9, r = q & 511, kl = r >> 4, cq = r & 15;
            float4 v = *(const float4*)&Wt[(((size_t)m * DIN + c0 + kl) << 6) + 4 * cq];
            *(float4*)&ws3[(m * KC + kl) * 64 + 4 * cq] = v;
        }
        __syncthreads();

#pragma unroll 4
        for (int k = 0; k < KC; k++) {
            float4 w0 = *(const float4*)&ws3[(0 * KC + k) * 64 + 4 * cg];
            float4 w1 = *(const float4*)&ws3[(1 * KC + k) * 64 + 4 * cg];
            float4 w2 = *(const float4*)&ws3[(2 * KC + k) * 64 + 4 * cg];
#pragma unroll
            for (int i = 0; i < 4; i++) {
                float xi = xs[(4 * ng + i) * LDX + k];
                al[i].x += xi * w0.x; al[i].y += xi * w0.y; al[i].z += xi * w0.z; al[i].w += xi * w0.w;
                ar[i].x += xi * w1.x; ar[i].y += xi * w1.y; ar[i].z += xi * w1.z; ar[i].w += xi * w1.w;
                av[i].x += xi * w2.x; av[i].y += xi * w2.y; av[i].z += xi * w2.z; av[i].w += xi * w2.w;
            }
        }
    }

    float4 b4 = ((const float4*)bvec)[cg];
    float4 r4 = ((const float4*)rb)[cg];
#pragma unroll
    for (int i = 0; i < 4; i++) {
        int n = nb0 + 4 * ng + i;
        if (n < NN) {
            ((float4*)&xl[(size_t)n * HID])[cg] = al[i];
            ((float4*)&xr[(size_t)n * HID])[cg] = ar[i];
            float4 o = av[i];
            o.x += b4.x + r4.x; o.y += b4.y + r4.y;
            o.z += b4.z + r4.z; o.w += b4.w + r4.w;
            ((float4*)&acc[(size_t)n * HID])[cg] = o;
        }
    }
}

// ---- fused per-dst attention: 8 edges x 8 channels per wave ----
__global__ __launch_bounds__(256) void k_attn_dst(
        const int* __restrict__ off, const int* __restrict__ srcs,
        const float* __restrict__ xl, const float* __restrict__ xr,
        const float* __restrict__ att, float* __restrict__ acc) {
    const int lane = threadIdx.x & 63;
    const int d = blockIdx.x * 4 + (threadIdx.x >> 6);
    if (d >= NN) return;
    const int e = lane >> 3;
    const int cg = lane & 7;

    const float4* xr4 = (const float4*)&xr[(size_t)d * HID + 8 * cg];
    float4 xra = xr4[0], xrb = xr4[1];
    const float4* at4 = (const float4*)&att[8 * cg];
    float4 ata = at4[0], atb = at4[1];

#define EDGE_LOGIT(S, XA, XB, T)                                               \
    {                                                                          \
        const float4* _x4 = (const float4*)&xl[(size_t)(S) * HID + 8 * cg];    \
        XA = _x4[0]; XB = _x4[1];                                              \
        float _ps;                                                             \
        float _v;                                                              \
        _v = XA.x + xra.x; _ps  = (fmaxf(_v,0.f) + NEG*fminf(_v,0.f)) * ata.x; \
        _v = XA.y + xra.y; _ps += (fmaxf(_v,0.f) + NEG*fminf(_v,0.f)) * ata.y; \
        _v = XA.z + xra.z; _ps += (fmaxf(_v,0.f) + NEG*fminf(_v,0.f)) * ata.z; \
        _v = XA.w + xra.w; _ps += (fmaxf(_v,0.f) + NEG*fminf(_v,0.f)) * ata.w; \
        _v = XB.x + xrb.x; _ps += (fmaxf(_v,0.f) + NEG*fminf(_v,0.f)) * atb.x; \
        _v = XB.y + xrb.y; _ps += (fmaxf(_v,0.f) + NEG*fminf(_v,0.f)) * atb.y; \
        _v = XB.z + xrb.z; _ps += (fmaxf(_v,0.f) + NEG*fminf(_v,0.f)) * atb.z; \
        _v = XB.w + xrb.w; _ps += (fmaxf(_v,0.f) + NEG*fminf(_v,0.f)) * atb.w; \
        _ps += __shfl_xor(_ps, 1, 64);                                         \
        _ps += __shfl_xor(_ps, 2, 64);                                         \
        _ps += __shfl_xor(_ps, 4, 64);                                         \
        T = _ps;                                                               \
    }

    float m, l;
    float4 oA, oB;
    {
        float4 xla, xlb; float t;
        EDGE_LOGIT(d, xla, xlb, t);
        m = t;
        bool own = (e == 0);
        l = own ? 1.f : 0.f;
        oA = own ? xla : make_float4(0.f, 0.f, 0.f, 0.f);
        oB = own ? xlb : make_float4(0.f, 0.f, 0.f, 0.f);
    }

    const int lo = off[d], deg = off[d + 1] - lo;
    for (int base = 0; base < deg; base += 8) {
        int nv = deg - base;
        int sv = 0;
        if (lane < 8) sv = srcs[lo + min(base + lane, deg - 1)];
        int s = __shfl(sv, e, 64);

        float4 xla, xlb; float t;
        EDGE_LOGIT(s, xla, xlb, t);
        if (e >= nv) t = -INFINITY;

        float cm = t;
        cm = fmaxf(cm, __shfl_xor(cm, 8, 64));
        cm = fmaxf(cm, __shfl_xor(cm, 16, 64));
        cm = fmaxf(cm, __shfl_xor(cm, 32, 64));
        float newm = fmaxf(m, cm);
        float corr = __expf(m - newm);
        float p = __expf(t - newm);
        m = newm;
        l = l * corr + p;
        oA.x = oA.x * corr + p * xla.x; oA.y = oA.y * corr + p * xla.y;
        oA.z = oA.z * corr + p * xla.z; oA.w = oA.w * corr + p * xla.w;
        oB.x = oB.x * corr + p * xlb.x; oB.y = oB.y * corr + p * xlb.y;
        oB.z = oB.z * corr + p * xlb.z; oB.w = oB.w * corr + p * xlb.w;
    }
#undef EDGE_LOGIT

#pragma unroll
    for (int w = 8; w <= 32; w <<= 1) {
        l    += __shfl_xor(l, w, 64);
        oA.x += __shfl_xor(oA.x, w, 64); oA.y += __shfl_xor(oA.y, w, 64);
        oA.z += __shfl_xor(oA.z, w, 64); oA.w += __shfl_xor(oA.w, w, 64);
        oB.x += __shfl_xor(oB.x, w, 64); oB.y += __shfl_xor(oB.y, w, 64);
        oB.z += __shfl_xor(oB.z, w, 64); oB.w += __shfl_xor(oB.w, w, 64);
    }

    if (e == 0) {
        float inv = 1.f / l;
        float4* a4 = (float4*)&acc[(size_t)d * HID + 8 * cg];
        float4 c0 = a4[0], c1 = a4[1];
        c0.x += oA.x * inv; c0.y += oA.y * inv;
        c0.z += oA.z * inv; c0.w += oA.w * inv;
        c1.x += oB.x * inv; c1.y += oB.y * inv;
        c1.z += oB.z * inv; c1.w += oB.w * inv;
        a4[0] = c0; a4[1] = c1;
    }
}

// ---- fused mean-pool + head: one block (512 thr) per graph ----
__global__ __launch_bounds__(512) void k_pool_final(
        const float* __restrict__ acc,
        const int* __restrict__ startg, const int* __restrict__ endg,
        const float* __restrict__ Wf, const float* __restrict__ bf_,
        float* __restrict__ out) {
    __shared__ float red[8][HID];
    const int g = blockIdx.x;
    const int c = threadIdx.x & 63;
    const int j = threadIdx.x >> 6;
    const int s = startg[g], epos = endg[g];

    float sum = 0.f;
    for (int n = s + j; n < epos; n += 8)
        sum += acc[(size_t)n * HID + c];
    red[j][c] = sum;
    __syncthreads();

    if (threadIdx.x < HID) {
        float tot = 0.f;
#pragma unroll
        for (int w = 0; w < 8; w++) tot += red[w][c];
        float cntf = (float)(epos - s);
        float v = tot / fmaxf(cntf, 1.f) * Wf[c];
#pragma unroll
        for (int o = 32; o; o >>= 1) v += __shfl_xor(v, o, 64);
        if (c == 0) out[g] = v + bf_[0];
    }
}

extern "C" void kernel_launch(void* const* d_in, const int* in_sizes, int n_in,
                              void* d_out, int out_size, void* d_ws, size_t ws_size,
                              hipStream_t stream) {
    const float* x   = (const float*)d_in[0];
    const int* eidx  = (const int*)d_in[1];
    const int* batch = (const int*)d_in[2];
    const int* esrc = eidx;
    const int* edst = eidx + NE;
    const float* Wf  = (const float*)d_in[21];
    const float* bfb = (const float*)d_in[22];

    float* wsf = (float*)d_ws;
    const size_t NN64 = (size_t)NN * HID;
    float* xl     = wsf;
    float* xr     = xl + NN64;
    float* acc0   = xr + NN64;
    float* acc1   = acc0 + NN64;
    int*   ccnt   = (int*)(acc1 + NN64);
    int*   startg = ccnt + NN;
    int*   endg   = startg + NG;
    int*   off    = endg + NG;
    int*   cursor = off + NN + 1;
    int*   part   = cursor + NN;
    int*   partSc = part + SNB;
    int*   srcs   = partSc + SNB;
    float* Wt0    = (float*)(srcs + NE);
    float* Wt1    = Wt0 + 3 * DIN0 * HID;
    float* Wt2    = Wt1 + 3 * HID * HID;
    float* Wts[3] = {Wt0, Wt1, Wt2};

    // weight pre-transpose (tiny) + CSR build + graph bounds
    k_wt<<<(3 * DIN0 * HID + 255) / 256, 256, 0, stream>>>(
        (const float*)d_in[3], (const float*)d_in[4], (const float*)d_in[7], Wt0, DIN0);
    k_wt<<<(3 * HID * HID + 255) / 256, 256, 0, stream>>>(
        (const float*)d_in[9], (const float*)d_in[10], (const float*)d_in[13], Wt1, HID);
    k_wt<<<(3 * HID * HID + 255) / 256, 256, 0, stream>>>(
        (const float*)d_in[15], (const float*)d_in[16], (const float*)d_in[19], Wt2, HID);

    k_zero_int<<<(NN + 2 * NG + 255) / 256, 256, 0, stream>>>(ccnt, NN + 2 * NG);
    k_hist<<<(NE + 255) / 256, 256, 0, stream>>>(edst, ccnt);
    k_scan_part<<<SNB, 256, 0, stream>>>(ccnt, part);
    k_scan_small<<<1, 64, 0, stream>>>(part, partSc);
    k_scan_emit<<<SNB, 256, 0, stream>>>(ccnt, partSc, off, cursor);
    k_scatter_ids<<<8 * SCAT_BPG, 256, 0, stream>>>(esrc, edst, cursor, srcs);
    k_bounds<<<(NN + 255) / 256, 256, 0, stream>>>(batch, startg, endg);

    float* accs[4] = {acc0, acc0, acc1, acc0};  // out of layer L = accs[L+1]
    const int gemm_grid = (NN + 63) / 64;
    for (int L = 0; L < 3; L++) {
        const float* att = (const float*)d_in[3 + L * 6 + 2];
        const float* b   = (const float*)d_in[3 + L * 6 + 3];
        const float* Rb  = (const float*)d_in[3 + L * 6 + 5];
        float* accOut = accs[L + 1];

        if (L == 0)
            k_gemm<DIN0, false><<<gemm_grid, 256, 0, stream>>>(
                x, Wts[0], b, Rb, xl, xr, accOut);
        else
            k_gemm<HID, true><<<gemm_grid, 256, 0, stream>>>(
                accs[L], Wts[L], b, Rb, xl, xr, accOut);

        k_attn_dst<<<(NN + 3) / 4, 256, 0, stream>>>(off, srcs, xl, xr, att, accOut);
    }

    k_pool_final<<<NG, 512, 0, stream>>>(accs[3], startg, endg, Wf, bfb, (float*)d_out);
}